// Round 11
// baseline (560.489 us; speedup 1.0000x reference)
//
#include <hip/hip_runtime.h>
#include <hip/hip_bf16.h>
#include <math.h>

#define B_    8
#define SEQ_  4096
#define CIN_  7
#define DM_   512
#define NL_   4
#define PL_   16
#define NP_   256
#define NS_   16
#define DC_   4
#define DI_   1024
#define DTR_  32
#define CD_   64
#define PRED_ 96
#define TOK_  (B_*NP_)   // 2048
#define KTOT_ (DM_*NP_)  // 131072
#define EPS_  1e-5f
#define CL_   16         // scan chunk length
#define NCH_  (NP_/CL_)  // 16 chunks

typedef unsigned short u16;
typedef __attribute__((ext_vector_type(8))) short short8;
typedef __attribute__((ext_vector_type(4))) float floatx4;

__device__ __forceinline__ float silu_f(float x){ return x / (1.f + __expf(-x)); }
__device__ __forceinline__ float softplus_f(float x){ return x > 20.f ? x : log1pf(__expf(x)); }
__device__ __forceinline__ u16 f2bf(float f){
  union { __hip_bfloat16 h; u16 u; } cv; cv.h = __float2bfloat16(f); return cv.u;
}
__device__ __forceinline__ float bf2f(u16 u){
  union { unsigned int i; float f; } cv; cv.i = ((unsigned int)u) << 16; return cv.f;
}
#define GLDS16(g, l) __builtin_amdgcn_global_load_lds( \
    (const __attribute__((address_space(1))) void*)(g), \
    (__attribute__((address_space(3))) void*)(l), 16, 0, 0)

// ---------------- LN over CIN=7 -> bf16 patch rows [2048][128] (zero-padded 112..127) ----------------
__global__ void ln7_kernel(const float* __restrict__ x, const float* __restrict__ g,
                           const float* __restrict__ b, u16* __restrict__ xpb){
  int i = blockIdx.x*256 + threadIdx.x; // over B*SEQ
  if (i >= B_*SEQ_) return;
  float v[CIN_]; float m = 0.f;
  #pragma unroll
  for (int c=0;c<CIN_;c++){ v[c]=x[i*CIN_+c]; m+=v[c]; }
  m *= (1.f/CIN_);
  float var = 0.f;
  #pragma unroll
  for (int c=0;c<CIN_;c++){ float d=v[c]-m; var+=d*d; }
  var *= (1.f/CIN_);
  float r = rsqrtf(var + EPS_);
  int bn = i >> 4, p = i & 15;            // token, pos-in-patch
  u16* row = xpb + (size_t)bn*128;
  #pragma unroll
  for (int c=0;c<CIN_;c++) row[c*16+p] = f2bf((v[c]-m)*r*g[c]+b[c]);
  row[112+p] = 0;
}

// ---------------- LN over DM=512, wave-per-token, bf16 out ----------------
__global__ __launch_bounds__(256) void ln512_kernel(const float* __restrict__ in,
    const float* __restrict__ g, const float* __restrict__ b, u16* __restrict__ outb){
  int tid = threadIdx.x;
  int wv = tid>>6, lane = tid&63;
  int t = blockIdx.x*4 + wv;
  const float4* row = (const float4*)(in + (size_t)t*DM_);
  float4 v0 = row[lane], v1 = row[64+lane];
  float s = v0.x+v0.y+v0.z+v0.w + v1.x+v1.y+v1.z+v1.w;
  #pragma unroll
  for (int o=1;o<64;o<<=1) s += __shfl_xor(s,o);
  float m = s*(1.f/DM_);
  float d0x=v0.x-m,d0y=v0.y-m,d0z=v0.z-m,d0w=v0.w-m;
  float d1x=v1.x-m,d1y=v1.y-m,d1z=v1.z-m,d1w=v1.w-m;
  float q = d0x*d0x+d0y*d0y+d0z*d0z+d0w*d0w + d1x*d1x+d1y*d1y+d1z*d1z+d1w*d1w;
  #pragma unroll
  for (int o=1;o<64;o<<=1) q += __shfl_xor(q,o);
  float r = rsqrtf(q*(1.f/DM_) + EPS_);
  float4 g0 = ((const float4*)g)[lane], g1 = ((const float4*)g)[64+lane];
  float4 b0 = ((const float4*)b)[lane], b1 = ((const float4*)b)[64+lane];
  float4 o0 = { d0x*r*g0.x+b0.x, d0y*r*g0.y+b0.y, d0z*r*g0.z+b0.z, d0w*r*g0.w+b0.w };
  float4 o1 = { d1x*r*g1.x+b1.x, d1y*r*g1.y+b1.y, d1z*r*g1.z+b1.z, d1w*r*g1.w+b1.w };
  ushort4 p0 = { f2bf(o0.x), f2bf(o0.y), f2bf(o0.z), f2bf(o0.w) };
  ushort4 p1 = { f2bf(o1.x), f2bf(o1.y), f2bf(o1.z), f2bf(o1.w) };
  ((ushort4*)(outb + (size_t)t*DM_))[lane]    = p0;
  ((ushort4*)(outb + (size_t)t*DM_))[64+lane] = p1;
}

// ---------------- bf16 MFMA NT GEMM: C[M,N](f32) = A[M,K]*B[N,K]^T (+bias) ----------------
template<int BM, int BN, bool ACC, bool BIAS>
__global__ __launch_bounds__(256) void gemm_bf16(const u16* __restrict__ A,
    const u16* __restrict__ Bw, float* __restrict__ C, const float* __restrict__ bias,
    int K, int lda, int ldb, int ldc){
  constexpr int MI = BM/32, NI = BN/32;
  __shared__ __align__(16) u16 As[BM*64];
  __shared__ __align__(16) u16 Bs[BN*64];
  int tid = threadIdx.x;
  int wave = __builtin_amdgcn_readfirstlane(tid>>6);
  int lane = tid&63;
  int wm = wave>>1, wn = wave&1;
  int quad = lane>>4, l16 = lane&15;
  int bm = blockIdx.y*BM, bn = blockIdx.x*BN;
  int r8 = lane>>3, sseg = lane&7;
  int gseg = sseg ^ r8;                  // global k-seg this lane fetches
  floatx4 acc[MI][NI] = {};
  for (int k0 = 0; k0 < K; k0 += 64){
    #pragma unroll
    for (int r = 0; r < BM/32; r++){
      int rowb = (r*4 + wave)*8;
      const u16* gp = A + (size_t)(bm + rowb + r8)*lda + k0 + gseg*8;
      GLDS16(gp, &As[rowb*64]);
    }
    #pragma unroll
    for (int r = 0; r < BN/32; r++){
      int rowb = (r*4 + wave)*8;
      const u16* gp = Bw + (size_t)(bn + rowb + r8)*ldb + k0 + gseg*8;
      GLDS16(gp, &Bs[rowb*64]);
    }
    __syncthreads();
    #pragma unroll
    for (int kh = 0; kh < 2; kh++){
      short8 af[MI], bfr[NI];
      #pragma unroll
      for (int i = 0; i < MI; i++){
        int row = wm*(BM/2)+i*16+l16;
        af[i] = *(short8*)&As[row*64 + (((kh*4+quad)^(row&7))*8)];
      }
      #pragma unroll
      for (int j = 0; j < NI; j++){
        int row = wn*(BN/2)+j*16+l16;
        bfr[j] = *(short8*)&Bs[row*64 + (((kh*4+quad)^(row&7))*8)];
      }
      #pragma unroll
      for (int i = 0; i < MI; i++)
        #pragma unroll
        for (int j = 0; j < NI; j++)
          acc[i][j] = __builtin_amdgcn_mfma_f32_16x16x32_bf16(af[i], bfr[j], acc[i][j], 0, 0, 0);
    }
    __syncthreads();
  }
  #pragma unroll
  for (int i = 0; i < MI; i++){
    #pragma unroll
    for (int j = 0; j < NI; j++){
      #pragma unroll
      for (int r = 0; r < 4; r++){
        int m  = bm + wm*(BM/2) + i*16 + quad*4 + r;
        int nn = bn + wn*(BN/2) + j*16 + l16;
        float v = acc[i][j][r];
        if (ACC) C[(size_t)m*ldc+nn] += v;
        else     C[(size_t)m*ldc+nn]  = BIAS ? v + bias[nn] : v;
      }
    }
  }
}

// ---------------- fused conv+silu -> LDS A-tile -> dbl split-K partial GEMM ----------------
// grid (TOK/64, 4 kc). Conv for (64t x 256c) computed into swizzled LDS + xcb global,
// then part[kc][64t][64e] = A-tile @ wxB[64e][kc-chunk]^T via MFMA.
__global__ __launch_bounds__(256) void convdbl_kernel(const float* __restrict__ xz,
    const float* __restrict__ cW, const float* __restrict__ cb,
    const u16* __restrict__ wxB, u16* __restrict__ xcb, float* __restrict__ part){
  __shared__ __align__(16) u16 As[64*256];   // 32 KB
  __shared__ __align__(16) u16 Bs[64*64];    // 8 KB
  int tid = threadIdx.x;
  int t0 = blockIdx.x*64;
  int kc = blockIdx.y;
  int cbase = kc*256;
  // ---- conv phase: thread = 8 channels (cg) x 8 t-rows ----
  {
    int cg = tid & 31;          // 8-channel group within 256-chunk
    int tq = tid >> 5;          // 0..7
    int c = cbase + cg*8;
    float wt[8][4], bias[8];
    #pragma unroll
    for (int j = 0; j < 8; j++){
      float4 w4 = *(const float4*)&cW[(size_t)(c+j)*DC_];
      wt[j][0]=w4.x; wt[j][1]=w4.y; wt[j][2]=w4.z; wt[j][3]=w4.w;
    }
    float4 bq0 = *(const float4*)&cb[c], bq1 = *(const float4*)&cb[c+4];
    bias[0]=bq0.x; bias[1]=bq0.y; bias[2]=bq0.z; bias[3]=bq0.w;
    bias[4]=bq1.x; bias[5]=bq1.y; bias[6]=bq1.z; bias[7]=bq1.w;
    #pragma unroll
    for (int r = 0; r < 8; r++){
      int trow = t0 + r*8 + tq;
      int l = trow & (NP_-1);
      float a[8];
      #pragma unroll
      for (int j = 0; j < 8; j++) a[j] = bias[j];
      #pragma unroll
      for (int tap = 0; tap < DC_; tap++){
        if (l + tap >= 3){
          const float* px = xz + (size_t)(trow + tap - 3)*(2*DI_) + c;
          float4 x0 = *(const float4*)px;
          float4 x1 = *(const float4*)(px + 4);
          a[0]+=x0.x*wt[0][tap]; a[1]+=x0.y*wt[1][tap];
          a[2]+=x0.z*wt[2][tap]; a[3]+=x0.w*wt[3][tap];
          a[4]+=x1.x*wt[4][tap]; a[5]+=x1.y*wt[5][tap];
          a[6]+=x1.z*wt[6][tap]; a[7]+=x1.w*wt[7][tap];
        }
      }
      union { u16 h[8]; int4 v; } pk;
      #pragma unroll
      for (int j = 0; j < 8; j++) pk.h[j] = f2bf(silu_f(a[j]));
      int trel = trow - t0;
      *(int4*)&As[trel*256 + ((cg ^ (trel&7))*8)] = pk.v;
      *(int4*)&xcb[(size_t)trow*DI_ + c] = pk.v;
    }
  }
  __syncthreads();
  // ---- MFMA phase ----
  int wave = __builtin_amdgcn_readfirstlane(tid>>6);
  int lane = tid&63;
  int wm = wave>>1, wn = wave&1;
  int quad = lane>>4, l16 = lane&15;
  int r8 = lane>>3, sseg = lane&7;
  int gseg = sseg ^ r8;
  floatx4 acc[2][2] = {};
  for (int sc = 0; sc < 4; sc++){
    int k0 = cbase + sc*64;
    #pragma unroll
    for (int r = 0; r < 2; r++){
      int rowb = (r*4 + wave)*8;
      GLDS16(wxB + (size_t)(rowb + r8)*DI_ + k0 + gseg*8, &Bs[rowb*64]);
    }
    __syncthreads();
    #pragma unroll
    for (int kh = 0; kh < 2; kh++){
      int lseg = sc*8 + kh*4 + quad;
      short8 af[2], bfr[2];
      #pragma unroll
      for (int i = 0; i < 2; i++){
        int row = wm*32 + i*16 + l16;
        af[i] = *(short8*)&As[row*256 + ((lseg ^ (row&7))*8)];
      }
      #pragma unroll
      for (int j = 0; j < 2; j++){
        int row = wn*32 + j*16 + l16;
        bfr[j] = *(short8*)&Bs[row*64 + (((kh*4+quad)^(row&7))*8)];
      }
      #pragma unroll
      for (int i = 0; i < 2; i++)
        #pragma unroll
        for (int j = 0; j < 2; j++)
          acc[i][j] = __builtin_amdgcn_mfma_f32_16x16x32_bf16(af[i], bfr[j], acc[i][j], 0, 0, 0);
    }
    __syncthreads();
  }
  float* dst = part + (size_t)kc*TOK_*64;
  #pragma unroll
  for (int i = 0; i < 2; i++)
    #pragma unroll
    for (int j = 0; j < 2; j++)
      #pragma unroll
      for (int r = 0; r < 4; r++){
        int m  = t0 + wm*32 + i*16 + quad*4 + r;
        int nn = wn*32 + j*16 + l16;
        dst[(size_t)m*64+nn] = acc[i][j][r];
      }
}

// ---------------- fused: dbl partial-sum -> delta -> scan pass A ----------------
// grid (4 dx, 128 bych). delta kept in registers for the scan; B/C cols -> LDS + global.
__global__ __launch_bounds__(256) void dscan_kernel(const float* __restrict__ part,
    const float* __restrict__ wdtT, const float* __restrict__ bdt,
    const u16* __restrict__ xcb, const float* __restrict__ Alog,
    float* __restrict__ dbl, float* __restrict__ delta,
    float* __restrict__ hend, float* __restrict__ aprod){
  __shared__ float sdt[CL_][32];
  __shared__ float sBC[CL_][32];
  int tid = threadIdx.x;
  int dx = blockIdx.x;
  int bych = blockIdx.y;
  int t0 = bych*CL_;
  for (int i = tid; i < CL_*64; i += 256){
    int t = i >> 6, col = i & 63;
    size_t o = (size_t)(t0+t)*64 + col;
    float s = part[o] + part[(size_t)TOK_*64 + o]
            + part[(size_t)2*TOK_*64 + o] + part[(size_t)3*TOK_*64 + o];
    if (col < 32) sdt[t][col] = s;
    else { sBC[t][col-32] = s; if (dx == 0) dbl[o] = s; }
  }
  int d = dx*256 + tid;
  float wv[DTR_];
  #pragma unroll
  for (int r = 0; r < DTR_; r++) wv[r] = wdtT[(size_t)r*DI_ + d];
  float bb = bdt[d];
  __syncthreads();
  float de[CL_];
  #pragma unroll 4
  for (int t = 0; t < CL_; t++){
    float acc = bb;
    #pragma unroll
    for (int r = 0; r < DTR_; r++) acc += sdt[t][r]*wv[r];
    de[t] = softplus_f(acc);
    delta[(size_t)(t0+t)*DI_ + d] = de[t];
  }
  float A[NS_], h[NS_], pr[NS_];
  #pragma unroll
  for (int k = 0; k < NS_; k++){
    A[k] = -__expf(Alog[(size_t)d*NS_ + k]);
    h[k] = 0.f; pr[k] = 1.f;
  }
  #pragma unroll
  for (int t = 0; t < CL_; t++){
    float xv = bf2f(xcb[(size_t)(t0+t)*DI_ + d]);
    float cde = de[t]*xv;
    #pragma unroll
    for (int k = 0; k < NS_; k++){
      float a = __expf(de[t]*A[k]);
      h[k] = a*h[k] + cde*sBC[t][k];
      pr[k] *= a;
    }
  }
  size_t o = ((size_t)bych*DI_ + d)*NS_;
  #pragma unroll
  for (int k = 0; k < NS_; k++){ hend[o+k] = h[k]; aprod[o+k] = pr[k]; }
}

__global__ __launch_bounds__(256) void scan_fix_kernel(const float* __restrict__ aprod,
    float* __restrict__ hend){
  int id = blockIdx.x*256 + threadIdx.x;  // over B*DI*NS = 131072
  int nd = id & (DI_*NS_ - 1);
  int b  = id >> 14;
  float h = 0.f;
  #pragma unroll
  for (int ch = 0; ch < NCH_; ch++){
    size_t idx = (size_t)(b*NCH_ + ch)*(DI_*NS_) + nd;
    float ap = aprod[idx];
    float he = hend[idx];
    hend[idx] = h;
    h = ap*h + he;
  }
}

__global__ __launch_bounds__(256) void scan_final_kernel(const float* __restrict__ delta,
    const u16* __restrict__ xcb, const float* __restrict__ dbl,
    const float* __restrict__ xz, const float* __restrict__ Dv,
    const float* __restrict__ Alog, const float* __restrict__ hin,
    u16* __restrict__ yb){
  __shared__ float sBC[CL_][32];
  int tid = threadIdx.x;
  int d = blockIdx.x*256 + tid;
  int bych = blockIdx.y;
  int base = bych*CL_;
  for (int i = tid; i < CL_*32; i += 256){
    int t = i >> 5, c = i & 31;
    sBC[t][c] = dbl[(size_t)(base+t)*64 + 32 + c];
  }
  float A[NS_], h[NS_];
  size_t o = ((size_t)bych*DI_ + d)*NS_;
  #pragma unroll
  for (int k = 0; k < NS_; k++){
    A[k] = -__expf(Alog[(size_t)d*NS_ + k]);
    h[k] = hin[o + k];
  }
  float Dvd = Dv[d];
  __syncthreads();
  #pragma unroll
  for (int t = 0; t < CL_; t++){
    int row = base + t;
    float de = delta[(size_t)row*DI_ + d];
    float xv = bf2f(xcb[(size_t)row*DI_ + d]);
    float zz = xz[(size_t)row*(2*DI_) + DI_ + d];
    float cde = de*xv;
    float p = 0.f;
    #pragma unroll
    for (int k = 0; k < NS_; k++){
      float a = __expf(de*A[k]);
      h[k] = a*h[k] + cde*sBC[t][k];
      p += h[k]*sBC[t][16+k];
    }
    yb[(size_t)row*DI_ + d] = f2bf((p + xv*Dvd) * silu_f(zz));
  }
}

// ---------------- head GEMM1 as MFMA: C[128n][8m], split-K 512, in-kernel fp32->bf16 ----------------
__global__ __launch_bounds__(256) void head1_kernel(const float* __restrict__ hW1,
    const u16* __restrict__ ub, float* __restrict__ partial){
  __shared__ __align__(16) u16 As[128*64];
  __shared__ __align__(16) u16 Bs[16*64];
  int tid = threadIdx.x;
  int wave = __builtin_amdgcn_readfirstlane(tid>>6);
  int lane = tid & 63, quad = lane>>4, l16 = lane&15;
  int kc = blockIdx.x;              // 0..511, KLEN=256
  int arow = tid & 127, apair = tid >> 7;
  floatx4 acc[2] = {};
  for (int sc = 0; sc < 4; sc++){
    int k0 = kc*256 + sc*64;
    const float* ap = hW1 + (size_t)arow*KTOT_ + k0 + apair*32;
    #pragma unroll
    for (int s = 0; s < 4; s++){
      float4 f0 = *(const float4*)(ap + s*8);
      float4 f1 = *(const float4*)(ap + s*8 + 4);
      union { u16 h[8]; int4 v; } pk;
      pk.h[0]=f2bf(f0.x); pk.h[1]=f2bf(f0.y); pk.h[2]=f2bf(f0.z); pk.h[3]=f2bf(f0.w);
      pk.h[4]=f2bf(f1.x); pk.h[5]=f2bf(f1.y); pk.h[6]=f2bf(f1.z); pk.h[7]=f2bf(f1.w);
      int seg = apair*4 + s;
      *(int4*)&As[arow*64 + ((seg^(arow&7))*8)] = pk.v;
    }
    if (tid < 128){
      int brow = tid >> 3, bseg = tid & 7;
      int4 bv = {0,0,0,0};
      if (brow < 8) bv = *(const int4*)&ub[(size_t)brow*KTOT_ + k0 + bseg*8];
      *(int4*)&Bs[brow*64 + ((bseg^(brow&7))*8)] = bv;
    }
    __syncthreads();
    #pragma unroll
    for (int kh = 0; kh < 2; kh++){
      short8 bf = *(short8*)&Bs[l16*64 + (((kh*4+quad)^(l16&7))*8)];
      #pragma unroll
      for (int i = 0; i < 2; i++){
        int row = wave*32 + i*16 + l16;
        short8 af = *(short8*)&As[row*64 + (((kh*4+quad)^(row&7))*8)];
        acc[i] = __builtin_amdgcn_mfma_f32_16x16x32_bf16(af, bf, acc[i], 0, 0, 0);
      }
    }
    __syncthreads();
  }
  if (l16 < 8){
    #pragma unroll
    for (int i = 0; i < 2; i++)
      #pragma unroll
      for (int r = 0; r < 4; r++){
        int n = wave*32 + i*16 + quad*4 + r;
        partial[(size_t)kc*1024 + n*8 + l16] = acc[i][r];
      }
  }
}

// stage 1: pp2[8][1024] = sum of 64 kc-partials each
__global__ void head_comb1_kernel(const float* __restrict__ partial, float* __restrict__ pp2){
  int out = blockIdx.x*256 + threadIdx.x;   // 0..1023
  int g = blockIdx.y;                        // 0..7
  const float* p = partial + (size_t)g*64*1024 + out;
  float s = 0.f;
  #pragma unroll 8
  for (int j = 0; j < 64; j++) s += p[(size_t)j*1024];
  pp2[g*1024 + out] = s;
}

// stage 2: t1[m*128+n] = gelu(hb1[n] + sum_g pp2)
__global__ void head_comb2_kernel(const float* __restrict__ pp2,
    const float* __restrict__ hb1, float* __restrict__ t1){
  int out = blockIdx.x*256 + threadIdx.x;   // 0..1023
  int n = out >> 3, m = out & 7;
  float s = hb1[n];
  #pragma unroll
  for (int g = 0; g < 8; g++) s += pp2[g*1024 + out];
  float ge = 0.5f*s*(1.f + erff(s*0.70710678118f));
  t1[m*128 + n] = ge;
}

__global__ void head2_kernel(const float* __restrict__ t1, const float* __restrict__ hW2,
                             const float* __restrict__ hb2, float* __restrict__ out){
  int idx = blockIdx.x*128 + threadIdx.x;  // 8*96
  if (idx >= B_*PRED_) return;
  int m = idx / PRED_, q = idx % PRED_;
  float s = hb2[q];
  #pragma unroll 16
  for (int k = 0; k < 2*CD_; k++) s += t1[m*128 + k]*hW2[q*128 + k];
  out[idx] = s;
}

// ---------------- prep: vectorized bf16 conversions + transposes ----------------
__global__ __launch_bounds__(256) void prep_kernel(const float* __restrict__ W_dt,
    const float* __restrict__ W_x, const float* __restrict__ W_in,
    const float* __restrict__ W_out, const float* __restrict__ peW,
    float* __restrict__ wdtT, u16* __restrict__ wxB,
    u16* __restrict__ WinB, u16* __restrict__ WoutB, u16* __restrict__ peWb){
  int idx = blockIdx.x*256 + threadIdx.x;   // 1,048,576 threads
  {
    float4 v = ((const float4*)W_in)[idx];
    ushort4 o = { f2bf(v.x), f2bf(v.y), f2bf(v.z), f2bf(v.w) };
    ((ushort4*)WinB)[idx] = o;
  }
  if (idx < 524288){
    float4 v = ((const float4*)W_out)[idx];
    ushort4 o = { f2bf(v.x), f2bf(v.y), f2bf(v.z), f2bf(v.w) };
    ((ushort4*)WoutB)[idx] = o;
  }
  if (idx < NL_*64*DI_/4){   // wxB: straight bf16 copy of W_x (NT layout already)
    float4 v = ((const float4*)W_x)[idx];
    ushort4 o = { f2bf(v.x), f2bf(v.y), f2bf(v.z), f2bf(v.w) };
    ((ushort4*)wxB)[idx] = o;
  }
  if (idx < NL_*DTR_*DI_){
    int l = idx / (DTR_*DI_); int rem = idx % (DTR_*DI_);
    int r = rem / DI_; int d = rem % DI_;
    wdtT[idx] = W_dt[((size_t)l*DI_ + d)*DTR_ + r];
  }
  if (idx < 512*128){
    int d = idx >> 7, kk = idx & 127;
    peWb[idx] = (kk < 112) ? f2bf(peW[d*112 + kk]) : (u16)0;
  }
}

extern "C" void kernel_launch(void* const* d_in, const int* in_sizes, int n_in,
                              void* d_out, int out_size, void* d_ws, size_t ws_size,
                              hipStream_t stream) {
  const float* x      = (const float*)d_in[0];
  const float* in_g   = (const float*)d_in[1];
  const float* in_b   = (const float*)d_in[2];
  const float* pe_W   = (const float*)d_in[3];
  const float* pe_b   = (const float*)d_in[4];
  const float* ln_g   = (const float*)d_in[5];
  const float* ln_b   = (const float*)d_in[6];
  const float* W_in   = (const float*)d_in[7];
  const float* conv_W = (const float*)d_in[8];
  const float* conv_b = (const float*)d_in[9];
  const float* W_x    = (const float*)d_in[10];
  const float* W_dt   = (const float*)d_in[11];
  const float* b_dt   = (const float*)d_in[12];
  const float* A_log  = (const float*)d_in[13];
  const float* Dskip  = (const float*)d_in[14];
  const float* W_out  = (const float*)d_in[15];
  const float* fn_g   = (const float*)d_in[16];
  const float* fn_b   = (const float*)d_in[17];
  const float* hW1    = (const float*)d_in[18];
  const float* hb1    = (const float*)d_in[19];
  const float* hW2    = (const float*)d_in[20];
  const float* hb2    = (const float*)d_in[21];

  float* ws    = (float*)d_ws;
  float* h     = ws;                    // 1,048,576 f
  float* un    = h     + 1048576;       // 1,048,576 f  (= dblpart scratch [4][2048][64])
  float* xz    = un    + 1048576;       // 4,194,304 f
  float* xc    = xz    + 4194304;       // 2,097,152 f  (first half = xcb bf16)
  float* dblb  = xc    + 2097152;       //   131,072 f
  float* delta = dblb  + 131072;        // 2,097,152 f
  float* y     = delta + 2097152;       // 2,097,152 f  (overlays: xpb prologue, hend scan)
  float* wdtT  = y     + 2097152;       //   131,072 f
  u16*   wxB   = (u16*)(wdtT + 131072);         //   262,144 u16 (=131,072 f)
  float* bf_rgn= wdtT + 131072 + 131072;
  u16*   unb   = (u16*)bf_rgn;                  // 1,048,576 u16
  u16*   yb    = (u16*)(bf_rgn + 524288);       // 2,097,152 u16
  u16*   WinB  = (u16*)(bf_rgn + 524288 + 1048576);            // 4,194,304 u16
  u16*   WoutB = (u16*)(bf_rgn + 524288 + 1048576 + 2097152);  // 2,097,152 u16
  u16*   peWb  = (u16*)(bf_rgn + 524288 + 1048576 + 2097152 + 1048576); // 65,536 u16
  float* aprod = bf_rgn + 524288 + 1048576 + 2097152 + 1048576 + 32768; // 2,097,152 f
  // end ≈ 79.3 MB
  float* hend  = y;                     // [B*NCH][DI][NS]; becomes hin after pass B
  u16*   xcb   = (u16*)xc;              // bf16 xc [2048][1024] (alive through scan_final)
  u16*   xpb   = (u16*)y;               // prologue-only: bf16 patches [2048][128]
  float* dblpart = un;                  // [4][2048][64] = 524,288 f (un is otherwise unused)
  float* partial = xz;                  // epilogue-only (512*1024 = 524,288 f)
  float* pp2     = xz + 524288;         // 8,192 f
  float* t1      = xz + 532480;         // 1,024 f

  prep_kernel<<<4096, 256, 0, stream>>>(W_dt, W_x, W_in, W_out, pe_W,
                                        wdtT, wxB, WinB, WoutB, peWb);
  ln7_kernel<<<(B_*SEQ_+255)/256, 256, 0, stream>>>(x, in_g, in_b, xpb);
  // patch-embed as bf16 GEMM: h[2048][512] = xpb[2048][128] @ peWb[512][128]^T + pe_b
  gemm_bf16<64,128,false,true><<<dim3(DM_/128, TOK_/64), 256, 0, stream>>>(
      xpb, peWb, h, pe_b, 128, 128, 128, DM_);

  for (int l = 0; l < NL_; l++){
    ln512_kernel<<<TOK_/4, 256, 0, stream>>>(h, ln_g + l*DM_, ln_b + l*DM_, unb);
    gemm_bf16<128,128,false,false><<<dim3(2*DI_/128, TOK_/128), 256, 0, stream>>>(
        unb, WinB + (size_t)l*2*DI_*DM_, xz, nullptr, DM_, DM_, DM_, 2*DI_);
    convdbl_kernel<<<dim3(TOK_/64, 4), 256, 0, stream>>>(
        xz, conv_W + (size_t)l*DI_*DC_, conv_b + (size_t)l*DI_,
        wxB + (size_t)l*64*DI_, xcb, dblpart);
    dscan_kernel<<<dim3(DI_/256, B_*NCH_), 256, 0, stream>>>(
        dblpart, wdtT + (size_t)l*DTR_*DI_, b_dt + (size_t)l*DI_,
        xcb, A_log + (size_t)l*DI_*NS_, dblb, delta, hend, aprod);
    scan_fix_kernel<<<(B_*DI_*NS_)/256, 256, 0, stream>>>(aprod, hend);
    scan_final_kernel<<<dim3(DI_/256, B_*NCH_), 256, 0, stream>>>(
        delta, xcb, dblb, xz, Dskip + (size_t)l*DI_, A_log + (size_t)l*DI_*NS_, hend, yb);
    gemm_bf16<64,64,true,false><<<dim3(DM_/64, TOK_/64), 256, 0, stream>>>(
        yb, WoutB + (size_t)l*DM_*DI_, h, nullptr, DI_, DI_, DI_, DM_);
  }

  ln512_kernel<<<TOK_/4, 256, 0, stream>>>(h, fn_g, fn_b, unb);
  head1_kernel<<<512, 256, 0, stream>>>(hW1, unb, partial);
  head_comb1_kernel<<<dim3(4, 8), 256, 0, stream>>>(partial, pp2);
  head_comb2_kernel<<<4, 256, 0, stream>>>(pp2, hb1, t1);
  head2_kernel<<<6, 128, 0, stream>>>(t1, hW2, hb2, (float*)d_out);
}

// Round 12
// 551.536 us; speedup vs baseline: 1.0162x; 1.0162x over previous
//
#include <hip/hip_runtime.h>
#include <hip/hip_bf16.h>
#include <math.h>

#define B_    8
#define SEQ_  4096
#define CIN_  7
#define DM_   512
#define NL_   4
#define PL_   16
#define NP_   256
#define NS_   16
#define DC_   4
#define DI_   1024
#define DTR_  32
#define CD_   64
#define PRED_ 96
#define TOK_  (B_*NP_)   // 2048
#define KTOT_ (DM_*NP_)  // 131072
#define EPS_  1e-5f
#define CL_   16         // scan chunk length
#define NCH_  (NP_/CL_)  // 16 chunks

typedef unsigned short u16;
typedef __attribute__((ext_vector_type(8))) short short8;
typedef __attribute__((ext_vector_type(4))) float floatx4;

__device__ __forceinline__ float silu_f(float x){ return x / (1.f + __expf(-x)); }
__device__ __forceinline__ float softplus_f(float x){ return x > 20.f ? x : log1pf(__expf(x)); }
__device__ __forceinline__ u16 f2bf(float f){
  union { __hip_bfloat16 h; u16 u; } cv; cv.h = __float2bfloat16(f); return cv.u;
}
__device__ __forceinline__ float bf2f(u16 u){
  union { unsigned int i; float f; } cv; cv.i = ((unsigned int)u) << 16; return cv.f;
}
#define GLDS16(g, l) __builtin_amdgcn_global_load_lds( \
    (const __attribute__((address_space(1))) void*)(g), \
    (__attribute__((address_space(3))) void*)(l), 16, 0, 0)

// ---------------- LN over CIN=7 -> bf16 patch rows [2048][128] (zero-padded 112..127) ----------------
__global__ void ln7_kernel(const float* __restrict__ x, const float* __restrict__ g,
                           const float* __restrict__ b, u16* __restrict__ xpb){
  int i = blockIdx.x*256 + threadIdx.x; // over B*SEQ
  if (i >= B_*SEQ_) return;
  float v[CIN_]; float m = 0.f;
  #pragma unroll
  for (int c=0;c<CIN_;c++){ v[c]=x[i*CIN_+c]; m+=v[c]; }
  m *= (1.f/CIN_);
  float var = 0.f;
  #pragma unroll
  for (int c=0;c<CIN_;c++){ float d=v[c]-m; var+=d*d; }
  var *= (1.f/CIN_);
  float r = rsqrtf(var + EPS_);
  int bn = i >> 4, p = i & 15;            // token, pos-in-patch
  u16* row = xpb + (size_t)bn*128;
  #pragma unroll
  for (int c=0;c<CIN_;c++) row[c*16+p] = f2bf((v[c]-m)*r*g[c]+b[c]);
  row[112+p] = 0;
}

// ---------------- LN over DM=512, wave-per-token, bf16 out ----------------
__global__ __launch_bounds__(256) void ln512_kernel(const float* __restrict__ in,
    const float* __restrict__ g, const float* __restrict__ b, u16* __restrict__ outb){
  int tid = threadIdx.x;
  int wv = tid>>6, lane = tid&63;
  int t = blockIdx.x*4 + wv;
  const float4* row = (const float4*)(in + (size_t)t*DM_);
  float4 v0 = row[lane], v1 = row[64+lane];
  float s = v0.x+v0.y+v0.z+v0.w + v1.x+v1.y+v1.z+v1.w;
  #pragma unroll
  for (int o=1;o<64;o<<=1) s += __shfl_xor(s,o);
  float m = s*(1.f/DM_);
  float d0x=v0.x-m,d0y=v0.y-m,d0z=v0.z-m,d0w=v0.w-m;
  float d1x=v1.x-m,d1y=v1.y-m,d1z=v1.z-m,d1w=v1.w-m;
  float q = d0x*d0x+d0y*d0y+d0z*d0z+d0w*d0w + d1x*d1x+d1y*d1y+d1z*d1z+d1w*d1w;
  #pragma unroll
  for (int o=1;o<64;o<<=1) q += __shfl_xor(q,o);
  float r = rsqrtf(q*(1.f/DM_) + EPS_);
  float4 g0 = ((const float4*)g)[lane], g1 = ((const float4*)g)[64+lane];
  float4 b0 = ((const float4*)b)[lane], b1 = ((const float4*)b)[64+lane];
  float4 o0 = { d0x*r*g0.x+b0.x, d0y*r*g0.y+b0.y, d0z*r*g0.z+b0.z, d0w*r*g0.w+b0.w };
  float4 o1 = { d1x*r*g1.x+b1.x, d1y*r*g1.y+b1.y, d1z*r*g1.z+b1.z, d1w*r*g1.w+b1.w };
  ushort4 p0 = { f2bf(o0.x), f2bf(o0.y), f2bf(o0.z), f2bf(o0.w) };
  ushort4 p1 = { f2bf(o1.x), f2bf(o1.y), f2bf(o1.z), f2bf(o1.w) };
  ((ushort4*)(outb + (size_t)t*DM_))[lane]    = p0;
  ((ushort4*)(outb + (size_t)t*DM_))[64+lane] = p1;
}

// ---------------- bf16 MFMA NT GEMM: C = A*B^T (+bias); OUTBF stores bf16 ----------------
template<int BM, int BN, bool ACC, bool BIAS, bool OUTBF>
__global__ __launch_bounds__(256) void gemm_bf16(const u16* __restrict__ A,
    const u16* __restrict__ Bw, void* __restrict__ Cv, const float* __restrict__ bias,
    int K, int lda, int ldb, int ldc){
  constexpr int MI = BM/32, NI = BN/32;
  __shared__ __align__(16) u16 As[BM*64];
  __shared__ __align__(16) u16 Bs[BN*64];
  int tid = threadIdx.x;
  int wave = __builtin_amdgcn_readfirstlane(tid>>6);
  int lane = tid&63;
  int wm = wave>>1, wn = wave&1;
  int quad = lane>>4, l16 = lane&15;
  int bm = blockIdx.y*BM, bn = blockIdx.x*BN;
  int r8 = lane>>3, sseg = lane&7;
  int gseg = sseg ^ r8;                  // global k-seg this lane fetches
  floatx4 acc[MI][NI] = {};
  for (int k0 = 0; k0 < K; k0 += 64){
    #pragma unroll
    for (int r = 0; r < BM/32; r++){
      int rowb = (r*4 + wave)*8;
      const u16* gp = A + (size_t)(bm + rowb + r8)*lda + k0 + gseg*8;
      GLDS16(gp, &As[rowb*64]);
    }
    #pragma unroll
    for (int r = 0; r < BN/32; r++){
      int rowb = (r*4 + wave)*8;
      const u16* gp = Bw + (size_t)(bn + rowb + r8)*ldb + k0 + gseg*8;
      GLDS16(gp, &Bs[rowb*64]);
    }
    __syncthreads();
    #pragma unroll
    for (int kh = 0; kh < 2; kh++){
      short8 af[MI], bfr[NI];
      #pragma unroll
      for (int i = 0; i < MI; i++){
        int row = wm*(BM/2)+i*16+l16;
        af[i] = *(short8*)&As[row*64 + (((kh*4+quad)^(row&7))*8)];
      }
      #pragma unroll
      for (int j = 0; j < NI; j++){
        int row = wn*(BN/2)+j*16+l16;
        bfr[j] = *(short8*)&Bs[row*64 + (((kh*4+quad)^(row&7))*8)];
      }
      #pragma unroll
      for (int i = 0; i < MI; i++)
        #pragma unroll
        for (int j = 0; j < NI; j++)
          acc[i][j] = __builtin_amdgcn_mfma_f32_16x16x32_bf16(af[i], bfr[j], acc[i][j], 0, 0, 0);
    }
    __syncthreads();
  }
  #pragma unroll
  for (int i = 0; i < MI; i++){
    #pragma unroll
    for (int j = 0; j < NI; j++){
      #pragma unroll
      for (int r = 0; r < 4; r++){
        int m  = bm + wm*(BM/2) + i*16 + quad*4 + r;
        int nn = bn + wn*(BN/2) + j*16 + l16;
        float v = acc[i][j][r];
        if (OUTBF){
          u16* C = (u16*)Cv;
          C[(size_t)m*ldc+nn] = f2bf(BIAS ? v + bias[nn] : v);
        } else {
          float* C = (float*)Cv;
          if (ACC) C[(size_t)m*ldc+nn] += v;
          else     C[(size_t)m*ldc+nn]  = BIAS ? v + bias[nn] : v;
        }
      }
    }
  }
}

// ---------------- fused conv+silu -> LDS A-tile -> dbl split-K partial GEMM (bf16 xz) ----------------
__global__ __launch_bounds__(256) void convdbl_kernel(const u16* __restrict__ xzb,
    const float* __restrict__ cW, const float* __restrict__ cb,
    const u16* __restrict__ wxB, u16* __restrict__ xcb, float* __restrict__ part){
  __shared__ __align__(16) u16 As[64*256];   // 32 KB
  __shared__ __align__(16) u16 Bs[64*64];    // 8 KB
  int tid = threadIdx.x;
  int t0 = blockIdx.x*64;
  int kc = blockIdx.y;
  int cbase = kc*256;
  // ---- conv phase: thread = 8 channels (cg) x 8 t-rows ----
  {
    int cg = tid & 31;          // 8-channel group within 256-chunk
    int tq = tid >> 5;          // 0..7
    int c = cbase + cg*8;
    float wt[8][4], bias[8];
    #pragma unroll
    for (int j = 0; j < 8; j++){
      float4 w4 = *(const float4*)&cW[(size_t)(c+j)*DC_];
      wt[j][0]=w4.x; wt[j][1]=w4.y; wt[j][2]=w4.z; wt[j][3]=w4.w;
    }
    float4 bq0 = *(const float4*)&cb[c], bq1 = *(const float4*)&cb[c+4];
    bias[0]=bq0.x; bias[1]=bq0.y; bias[2]=bq0.z; bias[3]=bq0.w;
    bias[4]=bq1.x; bias[5]=bq1.y; bias[6]=bq1.z; bias[7]=bq1.w;
    #pragma unroll
    for (int r = 0; r < 8; r++){
      int trow = t0 + r*8 + tq;
      int l = trow & (NP_-1);
      float a[8];
      #pragma unroll
      for (int j = 0; j < 8; j++) a[j] = bias[j];
      #pragma unroll
      for (int tap = 0; tap < DC_; tap++){
        if (l + tap >= 3){
          union { u16 h[8]; int4 v; } xv;
          xv.v = *(const int4*)&xzb[(size_t)(trow + tap - 3)*(2*DI_) + c];
          #pragma unroll
          for (int j = 0; j < 8; j++) a[j] += bf2f(xv.h[j])*wt[j][tap];
        }
      }
      union { u16 h[8]; int4 v; } pk;
      #pragma unroll
      for (int j = 0; j < 8; j++) pk.h[j] = f2bf(silu_f(a[j]));
      int trel = trow - t0;
      *(int4*)&As[trel*256 + ((cg ^ (trel&7))*8)] = pk.v;
      *(int4*)&xcb[(size_t)trow*DI_ + c] = pk.v;
    }
  }
  __syncthreads();
  // ---- MFMA phase ----
  int wave = __builtin_amdgcn_readfirstlane(tid>>6);
  int lane = tid&63;
  int wm = wave>>1, wn = wave&1;
  int quad = lane>>4, l16 = lane&15;
  int r8 = lane>>3, sseg = lane&7;
  int gseg = sseg ^ r8;
  floatx4 acc[2][2] = {};
  for (int sc = 0; sc < 4; sc++){
    int k0 = cbase + sc*64;
    #pragma unroll
    for (int r = 0; r < 2; r++){
      int rowb = (r*4 + wave)*8;
      GLDS16(wxB + (size_t)(rowb + r8)*DI_ + k0 + gseg*8, &Bs[rowb*64]);
    }
    __syncthreads();
    #pragma unroll
    for (int kh = 0; kh < 2; kh++){
      int lseg = sc*8 + kh*4 + quad;
      short8 af[2], bfr[2];
      #pragma unroll
      for (int i = 0; i < 2; i++){
        int row = wm*32 + i*16 + l16;
        af[i] = *(short8*)&As[row*256 + ((lseg ^ (row&7))*8)];
      }
      #pragma unroll
      for (int j = 0; j < 2; j++){
        int row = wn*32 + j*16 + l16;
        bfr[j] = *(short8*)&Bs[row*64 + (((kh*4+quad)^(row&7))*8)];
      }
      #pragma unroll
      for (int i = 0; i < 2; i++)
        #pragma unroll
        for (int j = 0; j < 2; j++)
          acc[i][j] = __builtin_amdgcn_mfma_f32_16x16x32_bf16(af[i], bfr[j], acc[i][j], 0, 0, 0);
    }
    __syncthreads();
  }
  float* dst = part + (size_t)kc*TOK_*64;
  #pragma unroll
  for (int i = 0; i < 2; i++)
    #pragma unroll
    for (int j = 0; j < 2; j++)
      #pragma unroll
      for (int r = 0; r < 4; r++){
        int m  = t0 + wm*32 + i*16 + quad*4 + r;
        int nn = wn*32 + j*16 + l16;
        dst[(size_t)m*64+nn] = acc[i][j][r];
      }
}

// ---------------- fused: dbl partial-sum -> delta(bf16) -> scan pass A ----------------
__global__ __launch_bounds__(256) void dscan_kernel(const float* __restrict__ part,
    const float* __restrict__ wdtT, const float* __restrict__ bdt,
    const u16* __restrict__ xcb, const float* __restrict__ Alog,
    float* __restrict__ dbl, u16* __restrict__ deltab,
    float* __restrict__ hend, float* __restrict__ aprod){
  __shared__ float sdt[CL_][32];
  __shared__ float sBC[CL_][32];
  int tid = threadIdx.x;
  int dx = blockIdx.x;
  int bych = blockIdx.y;
  int t0 = bych*CL_;
  for (int i = tid; i < CL_*64; i += 256){
    int t = i >> 6, col = i & 63;
    size_t o = (size_t)(t0+t)*64 + col;
    float s = part[o] + part[(size_t)TOK_*64 + o]
            + part[(size_t)2*TOK_*64 + o] + part[(size_t)3*TOK_*64 + o];
    if (col < 32) sdt[t][col] = s;
    else { sBC[t][col-32] = s; if (dx == 0) dbl[o] = s; }
  }
  int d = dx*256 + tid;
  float wv[DTR_];
  #pragma unroll
  for (int r = 0; r < DTR_; r++) wv[r] = wdtT[(size_t)r*DI_ + d];
  float bb = bdt[d];
  __syncthreads();
  float de[CL_];
  #pragma unroll 4
  for (int t = 0; t < CL_; t++){
    float acc = bb;
    #pragma unroll
    for (int r = 0; r < DTR_; r++) acc += sdt[t][r]*wv[r];
    u16 db = f2bf(softplus_f(acc));
    de[t] = bf2f(db);                    // use the bf16-rounded value for bit-consistency
    deltab[(size_t)(t0+t)*DI_ + d] = db;
  }
  float A[NS_], h[NS_], pr[NS_];
  #pragma unroll
  for (int k = 0; k < NS_; k++){
    A[k] = -__expf(Alog[(size_t)d*NS_ + k]);
    h[k] = 0.f; pr[k] = 1.f;
  }
  #pragma unroll
  for (int t = 0; t < CL_; t++){
    float xv = bf2f(xcb[(size_t)(t0+t)*DI_ + d]);
    float cde = de[t]*xv;
    #pragma unroll
    for (int k = 0; k < NS_; k++){
      float a = __expf(de[t]*A[k]);
      h[k] = a*h[k] + cde*sBC[t][k];
      pr[k] *= a;
    }
  }
  size_t o = ((size_t)bych*DI_ + d)*NS_;
  #pragma unroll
  for (int k = 0; k < NS_; k++){ hend[o+k] = h[k]; aprod[o+k] = pr[k]; }
}

__global__ __launch_bounds__(256) void scan_fix_kernel(const float* __restrict__ aprod,
    float* __restrict__ hend){
  int id = blockIdx.x*256 + threadIdx.x;  // over B*DI*NS = 131072
  int nd = id & (DI_*NS_ - 1);
  int b  = id >> 14;
  float h = 0.f;
  #pragma unroll
  for (int ch = 0; ch < NCH_; ch++){
    size_t idx = (size_t)(b*NCH_ + ch)*(DI_*NS_) + nd;
    float ap = aprod[idx];
    float he = hend[idx];
    hend[idx] = h;
    h = ap*h + he;
  }
}

__global__ __launch_bounds__(256) void scan_final_kernel(const u16* __restrict__ deltab,
    const u16* __restrict__ xcb, const float* __restrict__ dbl,
    const u16* __restrict__ xzb, const float* __restrict__ Dv,
    const float* __restrict__ Alog, const float* __restrict__ hin,
    u16* __restrict__ yb){
  __shared__ float sBC[CL_][32];
  int tid = threadIdx.x;
  int d = blockIdx.x*256 + tid;
  int bych = blockIdx.y;
  int base = bych*CL_;
  for (int i = tid; i < CL_*32; i += 256){
    int t = i >> 5, c = i & 31;
    sBC[t][c] = dbl[(size_t)(base+t)*64 + 32 + c];
  }
  float A[NS_], h[NS_];
  size_t o = ((size_t)bych*DI_ + d)*NS_;
  #pragma unroll
  for (int k = 0; k < NS_; k++){
    A[k] = -__expf(Alog[(size_t)d*NS_ + k]);
    h[k] = hin[o + k];
  }
  float Dvd = Dv[d];
  __syncthreads();
  #pragma unroll
  for (int t = 0; t < CL_; t++){
    int row = base + t;
    float de = bf2f(deltab[(size_t)row*DI_ + d]);
    float xv = bf2f(xcb[(size_t)row*DI_ + d]);
    float zz = bf2f(xzb[(size_t)row*(2*DI_) + DI_ + d]);
    float cde = de*xv;
    float p = 0.f;
    #pragma unroll
    for (int k = 0; k < NS_; k++){
      float a = __expf(de*A[k]);
      h[k] = a*h[k] + cde*sBC[t][k];
      p += h[k]*sBC[t][16+k];
    }
    yb[(size_t)row*DI_ + d] = f2bf((p + xv*Dvd) * silu_f(zz));
  }
}

// ---------------- head GEMM1 as MFMA: C[128n][8m], split-K 512, in-kernel fp32->bf16 ----------------
__global__ __launch_bounds__(256) void head1_kernel(const float* __restrict__ hW1,
    const u16* __restrict__ ub, float* __restrict__ partial){
  __shared__ __align__(16) u16 As[128*64];
  __shared__ __align__(16) u16 Bs[16*64];
  int tid = threadIdx.x;
  int wave = __builtin_amdgcn_readfirstlane(tid>>6);
  int lane = tid & 63, quad = lane>>4, l16 = lane&15;
  int kc = blockIdx.x;              // 0..511, KLEN=256
  int arow = tid & 127, apair = tid >> 7;
  floatx4 acc[2] = {};
  for (int sc = 0; sc < 4; sc++){
    int k0 = kc*256 + sc*64;
    const float* ap = hW1 + (size_t)arow*KTOT_ + k0 + apair*32;
    #pragma unroll
    for (int s = 0; s < 4; s++){
      float4 f0 = *(const float4*)(ap + s*8);
      float4 f1 = *(const float4*)(ap + s*8 + 4);
      union { u16 h[8]; int4 v; } pk;
      pk.h[0]=f2bf(f0.x); pk.h[1]=f2bf(f0.y); pk.h[2]=f2bf(f0.z); pk.h[3]=f2bf(f0.w);
      pk.h[4]=f2bf(f1.x); pk.h[5]=f2bf(f1.y); pk.h[6]=f2bf(f1.z); pk.h[7]=f2bf(f1.w);
      int seg = apair*4 + s;
      *(int4*)&As[arow*64 + ((seg^(arow&7))*8)] = pk.v;
    }
    if (tid < 128){
      int brow = tid >> 3, bseg = tid & 7;
      int4 bv = {0,0,0,0};
      if (brow < 8) bv = *(const int4*)&ub[(size_t)brow*KTOT_ + k0 + bseg*8];
      *(int4*)&Bs[brow*64 + ((bseg^(brow&7))*8)] = bv;
    }
    __syncthreads();
    #pragma unroll
    for (int kh = 0; kh < 2; kh++){
      short8 bf = *(short8*)&Bs[l16*64 + (((kh*4+quad)^(l16&7))*8)];
      #pragma unroll
      for (int i = 0; i < 2; i++){
        int row = wave*32 + i*16 + l16;
        short8 af = *(short8*)&As[row*64 + (((kh*4+quad)^(row&7))*8)];
        acc[i] = __builtin_amdgcn_mfma_f32_16x16x32_bf16(af, bf, acc[i], 0, 0, 0);
      }
    }
    __syncthreads();
  }
  if (l16 < 8){
    #pragma unroll
    for (int i = 0; i < 2; i++)
      #pragma unroll
      for (int r = 0; r < 4; r++){
        int n = wave*32 + i*16 + quad*4 + r;
        partial[(size_t)kc*1024 + n*8 + l16] = acc[i][r];
      }
  }
}

// stage 1: pp2[8][1024] = sum of 64 kc-partials each
__global__ void head_comb1_kernel(const float* __restrict__ partial, float* __restrict__ pp2){
  int out = blockIdx.x*256 + threadIdx.x;   // 0..1023
  int g = blockIdx.y;                        // 0..7
  const float* p = partial + (size_t)g*64*1024 + out;
  float s = 0.f;
  #pragma unroll 8
  for (int j = 0; j < 64; j++) s += p[(size_t)j*1024];
  pp2[g*1024 + out] = s;
}

// stage 2: t1[m*128+n] = gelu(hb1[n] + sum_g pp2)
__global__ void head_comb2_kernel(const float* __restrict__ pp2,
    const float* __restrict__ hb1, float* __restrict__ t1){
  int out = blockIdx.x*256 + threadIdx.x;   // 0..1023
  int n = out >> 3, m = out & 7;
  float s = hb1[n];
  #pragma unroll
  for (int g = 0; g < 8; g++) s += pp2[g*1024 + out];
  float ge = 0.5f*s*(1.f + erff(s*0.70710678118f));
  t1[m*128 + n] = ge;
}

__global__ void head2_kernel(const float* __restrict__ t1, const float* __restrict__ hW2,
                             const float* __restrict__ hb2, float* __restrict__ out){
  int idx = blockIdx.x*128 + threadIdx.x;  // 8*96
  if (idx >= B_*PRED_) return;
  int m = idx / PRED_, q = idx % PRED_;
  float s = hb2[q];
  #pragma unroll 16
  for (int k = 0; k < 2*CD_; k++) s += t1[m*128 + k]*hW2[q*128 + k];
  out[idx] = s;
}

// ---------------- prep: vectorized bf16 conversions + transposes ----------------
__global__ __launch_bounds__(256) void prep_kernel(const float* __restrict__ W_dt,
    const float* __restrict__ W_x, const float* __restrict__ W_in,
    const float* __restrict__ W_out, const float* __restrict__ peW,
    float* __restrict__ wdtT, u16* __restrict__ wxB,
    u16* __restrict__ WinB, u16* __restrict__ WoutB, u16* __restrict__ peWb){
  int idx = blockIdx.x*256 + threadIdx.x;   // 1,048,576 threads
  {
    float4 v = ((const float4*)W_in)[idx];
    ushort4 o = { f2bf(v.x), f2bf(v.y), f2bf(v.z), f2bf(v.w) };
    ((ushort4*)WinB)[idx] = o;
  }
  if (idx < 524288){
    float4 v = ((const float4*)W_out)[idx];
    ushort4 o = { f2bf(v.x), f2bf(v.y), f2bf(v.z), f2bf(v.w) };
    ((ushort4*)WoutB)[idx] = o;
  }
  if (idx < NL_*64*DI_/4){   // wxB: straight bf16 copy of W_x (NT layout already)
    float4 v = ((const float4*)W_x)[idx];
    ushort4 o = { f2bf(v.x), f2bf(v.y), f2bf(v.z), f2bf(v.w) };
    ((ushort4*)wxB)[idx] = o;
  }
  if (idx < NL_*DTR_*DI_){
    int l = idx / (DTR_*DI_); int rem = idx % (DTR_*DI_);
    int r = rem / DI_; int d = rem % DI_;
    wdtT[idx] = W_dt[((size_t)l*DI_ + d)*DTR_ + r];
  }
  if (idx < 512*128){
    int d = idx >> 7, kk = idx & 127;
    peWb[idx] = (kk < 112) ? f2bf(peW[d*112 + kk]) : (u16)0;
  }
}

extern "C" void kernel_launch(void* const* d_in, const int* in_sizes, int n_in,
                              void* d_out, int out_size, void* d_ws, size_t ws_size,
                              hipStream_t stream) {
  const float* x      = (const float*)d_in[0];
  const float* in_g   = (const float*)d_in[1];
  const float* in_b   = (const float*)d_in[2];
  const float* pe_W   = (const float*)d_in[3];
  const float* pe_b   = (const float*)d_in[4];
  const float* ln_g   = (const float*)d_in[5];
  const float* ln_b   = (const float*)d_in[6];
  const float* W_in   = (const float*)d_in[7];
  const float* conv_W = (const float*)d_in[8];
  const float* conv_b = (const float*)d_in[9];
  const float* W_x    = (const float*)d_in[10];
  const float* W_dt   = (const float*)d_in[11];
  const float* b_dt   = (const float*)d_in[12];
  const float* A_log  = (const float*)d_in[13];
  const float* Dskip  = (const float*)d_in[14];
  const float* W_out  = (const float*)d_in[15];
  const float* fn_g   = (const float*)d_in[16];
  const float* fn_b   = (const float*)d_in[17];
  const float* hW1    = (const float*)d_in[18];
  const float* hb1    = (const float*)d_in[19];
  const float* hW2    = (const float*)d_in[20];
  const float* hb2    = (const float*)d_in[21];

  float* ws    = (float*)d_ws;
  float* h     = ws;                    // 1,048,576 f
  float* un    = h     + 1048576;       // 1,048,576 f  (= dblpart scratch [4][2048][64])
  float* xz    = un    + 1048576;       // 4,194,304 f region (xzb u16 [2048][2048] = first half)
  float* xc    = xz    + 4194304;       // 2,097,152 f  (first half = xcb bf16)
  float* dblb  = xc    + 2097152;       //   131,072 f
  float* delta = dblb  + 131072;        // 2,097,152 f region (deltab u16 = first half)
  float* y     = delta + 2097152;       // 2,097,152 f  (overlays: xpb prologue, hend scan)
  float* wdtT  = y     + 2097152;       //   131,072 f
  u16*   wxB   = (u16*)(wdtT + 131072);         //   262,144 u16 (=131,072 f)
  float* bf_rgn= wdtT + 131072 + 131072;
  u16*   unb   = (u16*)bf_rgn;                  // 1,048,576 u16
  u16*   yb    = (u16*)(bf_rgn + 524288);       // 2,097,152 u16
  u16*   WinB  = (u16*)(bf_rgn + 524288 + 1048576);            // 4,194,304 u16
  u16*   WoutB = (u16*)(bf_rgn + 524288 + 1048576 + 2097152);  // 2,097,152 u16
  u16*   peWb  = (u16*)(bf_rgn + 524288 + 1048576 + 2097152 + 1048576); // 65,536 u16
  float* aprod = bf_rgn + 524288 + 1048576 + 2097152 + 1048576 + 32768; // 2,097,152 f
  // end ≈ 79.3 MB
  float* hend  = y;                     // [B*NCH][DI][NS]; becomes hin after pass B
  u16*   xcb   = (u16*)xc;              // bf16 xc [2048][1024] (alive through scan_final)
  u16*   xzb   = (u16*)xz;              // bf16 xz [2048][2048]
  u16*   deltab= (u16*)delta;           // bf16 delta [2048][1024]
  u16*   xpb   = (u16*)y;               // prologue-only: bf16 patches [2048][128]
  float* dblpart = un;                  // [4][2048][64] = 524,288 f
  float* partial = xz + 2097152;        // epilogue-only (512*1024 = 524,288 f; second half of xz region)
  float* pp2     = xz + 2097152 + 524288; // 8,192 f
  float* t1      = xz + 2097152 + 532480; // 1,024 f

  prep_kernel<<<4096, 256, 0, stream>>>(W_dt, W_x, W_in, W_out, pe_W,
                                        wdtT, wxB, WinB, WoutB, peWb);
  ln7_kernel<<<(B_*SEQ_+255)/256, 256, 0, stream>>>(x, in_g, in_b, xpb);
  // patch-embed as bf16 GEMM: h[2048][512] = xpb[2048][128] @ peWb[512][128]^T + pe_b
  gemm_bf16<64,128,false,true,false><<<dim3(DM_/128, TOK_/64), 256, 0, stream>>>(
      xpb, peWb, h, pe_b, 128, 128, 128, DM_);

  for (int l = 0; l < NL_; l++){
    ln512_kernel<<<TOK_/4, 256, 0, stream>>>(h, ln_g + l*DM_, ln_b + l*DM_, unb);
    gemm_bf16<128,128,false,false,true><<<dim3(2*DI_/128, TOK_/128), 256, 0, stream>>>(
        unb, WinB + (size_t)l*2*DI_*DM_, xzb, nullptr, DM_, DM_, DM_, 2*DI_);
    convdbl_kernel<<<dim3(TOK_/64, 4), 256, 0, stream>>>(
        xzb, conv_W + (size_t)l*DI_*DC_, conv_b + (size_t)l*DI_,
        wxB + (size_t)l*64*DI_, xcb, dblpart);
    dscan_kernel<<<dim3(DI_/256, B_*NCH_), 256, 0, stream>>>(
        dblpart, wdtT + (size_t)l*DTR_*DI_, b_dt + (size_t)l*DI_,
        xcb, A_log + (size_t)l*DI_*NS_, dblb, deltab, hend, aprod);
    scan_fix_kernel<<<(B_*DI_*NS_)/256, 256, 0, stream>>>(aprod, hend);
    scan_final_kernel<<<dim3(DI_/256, B_*NCH_), 256, 0, stream>>>(
        deltab, xcb, dblb, xzb, Dskip + (size_t)l*DI_, A_log + (size_t)l*DI_*NS_, hend, yb);
    gemm_bf16<64,64,true,false,false><<<dim3(DM_/64, TOK_/64), 256, 0, stream>>>(
        yb, WoutB + (size_t)l*DM_*DI_, h, nullptr, DI_, DI_, DI_, DM_);
  }

  ln512_kernel<<<TOK_/4, 256, 0, stream>>>(h, fn_g, fn_b, unb);
  head1_kernel<<<512, 256, 0, stream>>>(hW1, unb, partial);
  head_comb1_kernel<<<dim3(4, 8), 256, 0, stream>>>(partial, pp2);
  head_comb2_kernel<<<4, 256, 0, stream>>>(pp2, hb1, t1);
  head2_kernel<<<6, 128, 0, stream>>>(t1, hW2, hb2, (float*)d_out);
}

// Round 13
// 540.689 us; speedup vs baseline: 1.0366x; 1.0201x over previous
//
#include <hip/hip_runtime.h>
#include <hip/hip_bf16.h>
#include <math.h>

#define B_    8
#define SEQ_  4096
#define CIN_  7
#define DM_   512
#define NL_   4
#define PL_   16
#define NP_   256
#define NS_   16
#define DC_   4
#define DI_   1024
#define DTR_  32
#define CD_   64
#define PRED_ 96
#define TOK_  (B_*NP_)   // 2048
#define KTOT_ (DM_*NP_)  // 131072
#define EPS_  1e-5f
#define CL_   16         // scan chunk length
#define NCH_  (NP_/CL_)  // 16 chunks

typedef unsigned short u16;
typedef __attribute__((ext_vector_type(8))) short short8;
typedef __attribute__((ext_vector_type(4))) float floatx4;

__device__ __forceinline__ float silu_f(float x){ return x / (1.f + __expf(-x)); }
__device__ __forceinline__ float softplus_f(float x){ return x > 20.f ? x : log1pf(__expf(x)); }
__device__ __forceinline__ u16 f2bf(float f){
  union { __hip_bfloat16 h; u16 u; } cv; cv.h = __float2bfloat16(f); return cv.u;
}
__device__ __forceinline__ float bf2f(u16 u){
  union { unsigned int i; float f; } cv; cv.i = ((unsigned int)u) << 16; return cv.f;
}
#define GLDS16(g, l) __builtin_amdgcn_global_load_lds( \
    (const __attribute__((address_space(1))) void*)(g), \
    (__attribute__((address_space(3))) void*)(l), 16, 0, 0)

// ---------------- LN over CIN=7 -> bf16 patch rows [2048][128] (zero-padded 112..127) ----------------
__global__ void ln7_kernel(const float* __restrict__ x, const float* __restrict__ g,
                           const float* __restrict__ b, u16* __restrict__ xpb){
  int i = blockIdx.x*256 + threadIdx.x; // over B*SEQ
  if (i >= B_*SEQ_) return;
  float v[CIN_]; float m = 0.f;
  #pragma unroll
  for (int c=0;c<CIN_;c++){ v[c]=x[i*CIN_+c]; m+=v[c]; }
  m *= (1.f/CIN_);
  float var = 0.f;
  #pragma unroll
  for (int c=0;c<CIN_;c++){ float d=v[c]-m; var+=d*d; }
  var *= (1.f/CIN_);
  float r = rsqrtf(var + EPS_);
  int bn = i >> 4, p = i & 15;            // token, pos-in-patch
  u16* row = xpb + (size_t)bn*128;
  #pragma unroll
  for (int c=0;c<CIN_;c++) row[c*16+p] = f2bf((v[c]-m)*r*g[c]+b[c]);
  row[112+p] = 0;
}

// ---------------- LN over DM=512, wave-per-token, bf16 out ----------------
__global__ __launch_bounds__(256) void ln512_kernel(const float* __restrict__ in,
    const float* __restrict__ g, const float* __restrict__ b, u16* __restrict__ outb){
  int tid = threadIdx.x;
  int wv = tid>>6, lane = tid&63;
  int t = blockIdx.x*4 + wv;
  const float4* row = (const float4*)(in + (size_t)t*DM_);
  float4 v0 = row[lane], v1 = row[64+lane];
  float s = v0.x+v0.y+v0.z+v0.w + v1.x+v1.y+v1.z+v1.w;
  #pragma unroll
  for (int o=1;o<64;o<<=1) s += __shfl_xor(s,o);
  float m = s*(1.f/DM_);
  float d0x=v0.x-m,d0y=v0.y-m,d0z=v0.z-m,d0w=v0.w-m;
  float d1x=v1.x-m,d1y=v1.y-m,d1z=v1.z-m,d1w=v1.w-m;
  float q = d0x*d0x+d0y*d0y+d0z*d0z+d0w*d0w + d1x*d1x+d1y*d1y+d1z*d1z+d1w*d1w;
  #pragma unroll
  for (int o=1;o<64;o<<=1) q += __shfl_xor(q,o);
  float r = rsqrtf(q*(1.f/DM_) + EPS_);
  float4 g0 = ((const float4*)g)[lane], g1 = ((const float4*)g)[64+lane];
  float4 b0 = ((const float4*)b)[lane], b1 = ((const float4*)b)[64+lane];
  float4 o0 = { d0x*r*g0.x+b0.x, d0y*r*g0.y+b0.y, d0z*r*g0.z+b0.z, d0w*r*g0.w+b0.w };
  float4 o1 = { d1x*r*g1.x+b1.x, d1y*r*g1.y+b1.y, d1z*r*g1.z+b1.z, d1w*r*g1.w+b1.w };
  ushort4 p0 = { f2bf(o0.x), f2bf(o0.y), f2bf(o0.z), f2bf(o0.w) };
  ushort4 p1 = { f2bf(o1.x), f2bf(o1.y), f2bf(o1.z), f2bf(o1.w) };
  ((ushort4*)(outb + (size_t)t*DM_))[lane]    = p0;
  ((ushort4*)(outb + (size_t)t*DM_))[64+lane] = p1;
}

// ---------------- bf16 MFMA NT GEMM: C = A*B^T (+bias); OUTBF stores bf16 ----------------
template<int BM, int BN, bool ACC, bool BIAS, bool OUTBF>
__global__ __launch_bounds__(256) void gemm_bf16(const u16* __restrict__ A,
    const u16* __restrict__ Bw, void* __restrict__ Cv, const float* __restrict__ bias,
    int K, int lda, int ldb, int ldc){
  constexpr int MI = BM/32, NI = BN/32;
  __shared__ __align__(16) u16 As[BM*64];
  __shared__ __align__(16) u16 Bs[BN*64];
  int tid = threadIdx.x;
  int wave = __builtin_amdgcn_readfirstlane(tid>>6);
  int lane = tid&63;
  int wm = wave>>1, wn = wave&1;
  int quad = lane>>4, l16 = lane&15;
  int bm = blockIdx.y*BM, bn = blockIdx.x*BN;
  int r8 = lane>>3, sseg = lane&7;
  int gseg = sseg ^ r8;                  // global k-seg this lane fetches
  floatx4 acc[MI][NI] = {};
  for (int k0 = 0; k0 < K; k0 += 64){
    #pragma unroll
    for (int r = 0; r < BM/32; r++){
      int rowb = (r*4 + wave)*8;
      const u16* gp = A + (size_t)(bm + rowb + r8)*lda + k0 + gseg*8;
      GLDS16(gp, &As[rowb*64]);
    }
    #pragma unroll
    for (int r = 0; r < BN/32; r++){
      int rowb = (r*4 + wave)*8;
      const u16* gp = Bw + (size_t)(bn + rowb + r8)*ldb + k0 + gseg*8;
      GLDS16(gp, &Bs[rowb*64]);
    }
    __syncthreads();
    #pragma unroll
    for (int kh = 0; kh < 2; kh++){
      short8 af[MI], bfr[NI];
      #pragma unroll
      for (int i = 0; i < MI; i++){
        int row = wm*(BM/2)+i*16+l16;
        af[i] = *(short8*)&As[row*64 + (((kh*4+quad)^(row&7))*8)];
      }
      #pragma unroll
      for (int j = 0; j < NI; j++){
        int row = wn*(BN/2)+j*16+l16;
        bfr[j] = *(short8*)&Bs[row*64 + (((kh*4+quad)^(row&7))*8)];
      }
      #pragma unroll
      for (int i = 0; i < MI; i++)
        #pragma unroll
        for (int j = 0; j < NI; j++)
          acc[i][j] = __builtin_amdgcn_mfma_f32_16x16x32_bf16(af[i], bfr[j], acc[i][j], 0, 0, 0);
    }
    __syncthreads();
  }
  #pragma unroll
  for (int i = 0; i < MI; i++){
    #pragma unroll
    for (int j = 0; j < NI; j++){
      #pragma unroll
      for (int r = 0; r < 4; r++){
        int m  = bm + wm*(BM/2) + i*16 + quad*4 + r;
        int nn = bn + wn*(BN/2) + j*16 + l16;
        float v = acc[i][j][r];
        if (OUTBF){
          u16* C = (u16*)Cv;
          C[(size_t)m*ldc+nn] = f2bf(BIAS ? v + bias[nn] : v);
        } else {
          float* C = (float*)Cv;
          if (ACC) C[(size_t)m*ldc+nn] += v;
          else     C[(size_t)m*ldc+nn]  = BIAS ? v + bias[nn] : v;
        }
      }
    }
  }
}

// ---------------- fused conv+silu -> LDS A-tile -> dbl split-K partial GEMM (bf16 xz) ----------------
// grid (TOK/64, 8 kc), K-chunk = 128. part[kc][64t][64e].
__global__ __launch_bounds__(256) void convdbl_kernel(const u16* __restrict__ xzb,
    const float* __restrict__ cW, const float* __restrict__ cb,
    const u16* __restrict__ wxB, u16* __restrict__ xcb, float* __restrict__ part){
  __shared__ __align__(16) u16 As[64*128];   // 16 KB
  __shared__ __align__(16) u16 Bs[64*64];    // 8 KB
  int tid = threadIdx.x;
  int t0 = blockIdx.x*64;
  int kc = blockIdx.y;                 // 0..7
  int cbase = kc*128;
  // ---- conv phase: thread = 8 channels (cg of 16) x 4 t-rows (tq of 16) ----
  {
    int cg = tid & 15;
    int tq = tid >> 4;                 // 0..15
    int c = cbase + cg*8;
    float wt[8][4], bias[8];
    #pragma unroll
    for (int j = 0; j < 8; j++){
      float4 w4 = *(const float4*)&cW[(size_t)(c+j)*DC_];
      wt[j][0]=w4.x; wt[j][1]=w4.y; wt[j][2]=w4.z; wt[j][3]=w4.w;
    }
    float4 bq0 = *(const float4*)&cb[c], bq1 = *(const float4*)&cb[c+4];
    bias[0]=bq0.x; bias[1]=bq0.y; bias[2]=bq0.z; bias[3]=bq0.w;
    bias[4]=bq1.x; bias[5]=bq1.y; bias[6]=bq1.z; bias[7]=bq1.w;
    #pragma unroll
    for (int r = 0; r < 4; r++){
      int trow = t0 + r*16 + tq;
      int l = trow & (NP_-1);
      float a[8];
      #pragma unroll
      for (int j = 0; j < 8; j++) a[j] = bias[j];
      #pragma unroll
      for (int tap = 0; tap < DC_; tap++){
        if (l + tap >= 3){
          union { u16 h[8]; int4 v; } xv;
          xv.v = *(const int4*)&xzb[(size_t)(trow + tap - 3)*(2*DI_) + c];
          #pragma unroll
          for (int j = 0; j < 8; j++) a[j] += bf2f(xv.h[j])*wt[j][tap];
        }
      }
      union { u16 h[8]; int4 v; } pk;
      #pragma unroll
      for (int j = 0; j < 8; j++) pk.h[j] = f2bf(silu_f(a[j]));
      int trel = trow - t0;
      *(int4*)&As[trel*128 + ((cg ^ (trel&7))*8)] = pk.v;
      *(int4*)&xcb[(size_t)trow*DI_ + c] = pk.v;
    }
  }
  __syncthreads();
  // ---- MFMA phase ----
  int wave = __builtin_amdgcn_readfirstlane(tid>>6);
  int lane = tid&63;
  int wm = wave>>1, wn = wave&1;
  int quad = lane>>4, l16 = lane&15;
  int r8 = lane>>3, sseg = lane&7;
  int gseg = sseg ^ r8;
  floatx4 acc[2][2] = {};
  for (int sc = 0; sc < 2; sc++){
    int k0 = cbase + sc*64;
    #pragma unroll
    for (int r = 0; r < 2; r++){
      int rowb = (r*4 + wave)*8;
      GLDS16(wxB + (size_t)(rowb + r8)*DI_ + k0 + gseg*8, &Bs[rowb*64]);
    }
    __syncthreads();
    #pragma unroll
    for (int kh = 0; kh < 2; kh++){
      int lseg = sc*8 + kh*4 + quad;   // 0..15
      short8 af[2], bfr[2];
      #pragma unroll
      for (int i = 0; i < 2; i++){
        int row = wm*32 + i*16 + l16;
        af[i] = *(short8*)&As[row*128 + ((lseg ^ (row&7))*8)];
      }
      #pragma unroll
      for (int j = 0; j < 2; j++){
        int row = wn*32 + j*16 + l16;
        bfr[j] = *(short8*)&Bs[row*64 + (((kh*4+quad)^(row&7))*8)];
      }
      #pragma unroll
      for (int i = 0; i < 2; i++)
        #pragma unroll
        for (int j = 0; j < 2; j++)
          acc[i][j] = __builtin_amdgcn_mfma_f32_16x16x32_bf16(af[i], bfr[j], acc[i][j], 0, 0, 0);
    }
    __syncthreads();
  }
  float* dst = part + (size_t)kc*TOK_*64;
  #pragma unroll
  for (int i = 0; i < 2; i++)
    #pragma unroll
    for (int j = 0; j < 2; j++)
      #pragma unroll
      for (int r = 0; r < 4; r++){
        int m  = t0 + wm*32 + i*16 + quad*4 + r;
        int nn = wn*32 + j*16 + l16;
        dst[(size_t)m*64+nn] = acc[i][j][r];
      }
}

// ---------------- fused: dbl partial-sum (8) -> delta(bf16) -> scan pass A ----------------
__global__ __launch_bounds__(256) void dscan_kernel(const float* __restrict__ part,
    const float* __restrict__ wdtT, const float* __restrict__ bdt,
    const u16* __restrict__ xcb, const float* __restrict__ Alog,
    float* __restrict__ dbl, u16* __restrict__ deltab,
    float* __restrict__ hend, float* __restrict__ aprod){
  __shared__ float sdt[CL_][32];
  __shared__ float sBC[CL_][32];
  int tid = threadIdx.x;
  int dx = blockIdx.x;
  int bych = blockIdx.y;
  int t0 = bych*CL_;
  for (int i = tid; i < CL_*64; i += 256){
    int t = i >> 6, col = i & 63;
    size_t o = (size_t)(t0+t)*64 + col;
    float s = 0.f;
    #pragma unroll
    for (int kc = 0; kc < 8; kc++) s += part[(size_t)kc*TOK_*64 + o];
    if (col < 32) sdt[t][col] = s;
    else { sBC[t][col-32] = s; if (dx == 0) dbl[o] = s; }
  }
  int d = dx*256 + tid;
  float wv[DTR_];
  #pragma unroll
  for (int r = 0; r < DTR_; r++) wv[r] = wdtT[(size_t)r*DI_ + d];
  float bb = bdt[d];
  __syncthreads();
  float de[CL_];
  #pragma unroll 4
  for (int t = 0; t < CL_; t++){
    float acc = bb;
    #pragma unroll
    for (int r = 0; r < DTR_; r++) acc += sdt[t][r]*wv[r];
    u16 db = f2bf(softplus_f(acc));
    de[t] = bf2f(db);                    // use the bf16-rounded value for bit-consistency
    deltab[(size_t)(t0+t)*DI_ + d] = db;
  }
  float A[NS_], h[NS_], pr[NS_];
  #pragma unroll
  for (int k = 0; k < NS_; k++){
    A[k] = -__expf(Alog[(size_t)d*NS_ + k]);
    h[k] = 0.f; pr[k] = 1.f;
  }
  #pragma unroll
  for (int t = 0; t < CL_; t++){
    float xv = bf2f(xcb[(size_t)(t0+t)*DI_ + d]);
    float cde = de[t]*xv;
    #pragma unroll
    for (int k = 0; k < NS_; k++){
      float a = __expf(de[t]*A[k]);
      h[k] = a*h[k] + cde*sBC[t][k];
      pr[k] *= a;
    }
  }
  size_t o = ((size_t)bych*DI_ + d)*NS_;
  #pragma unroll
  for (int k = 0; k < NS_; k++){ hend[o+k] = h[k]; aprod[o+k] = pr[k]; }
}

__global__ __launch_bounds__(256) void scan_fix_kernel(const float* __restrict__ aprod,
    float* __restrict__ hend){
  int id = blockIdx.x*256 + threadIdx.x;  // over B*DI*NS = 131072
  int nd = id & (DI_*NS_ - 1);
  int b  = id >> 14;
  float h = 0.f;
  #pragma unroll
  for (int ch = 0; ch < NCH_; ch++){
    size_t idx = (size_t)(b*NCH_ + ch)*(DI_*NS_) + nd;
    float ap = aprod[idx];
    float he = hend[idx];
    hend[idx] = h;
    h = ap*h + he;
  }
}

__global__ __launch_bounds__(256) void scan_final_kernel(const u16* __restrict__ deltab,
    const u16* __restrict__ xcb, const float* __restrict__ dbl,
    const u16* __restrict__ xzb, const float* __restrict__ Dv,
    const float* __restrict__ Alog, const float* __restrict__ hin,
    u16* __restrict__ yb){
  __shared__ float sBC[CL_][32];
  int tid = threadIdx.x;
  int d = blockIdx.x*256 + tid;
  int bych = blockIdx.y;
  int base = bych*CL_;
  for (int i = tid; i < CL_*32; i += 256){
    int t = i >> 5, c = i & 31;
    sBC[t][c] = dbl[(size_t)(base+t)*64 + 32 + c];
  }
  float A[NS_], h[NS_];
  size_t o = ((size_t)bych*DI_ + d)*NS_;
  #pragma unroll
  for (int k = 0; k < NS_; k++){
    A[k] = -__expf(Alog[(size_t)d*NS_ + k]);
    h[k] = hin[o + k];
  }
  float Dvd = Dv[d];
  __syncthreads();
  #pragma unroll
  for (int t = 0; t < CL_; t++){
    int row = base + t;
    float de = bf2f(deltab[(size_t)row*DI_ + d]);
    float xv = bf2f(xcb[(size_t)row*DI_ + d]);
    float zz = bf2f(xzb[(size_t)row*(2*DI_) + DI_ + d]);
    float cde = de*xv;
    float p = 0.f;
    #pragma unroll
    for (int k = 0; k < NS_; k++){
      float a = __expf(de*A[k]);
      h[k] = a*h[k] + cde*sBC[t][k];
      p += h[k]*sBC[t][16+k];
    }
    yb[(size_t)row*DI_ + d] = f2bf((p + xv*Dvd) * silu_f(zz));
  }
}

// ---------------- head GEMM1 as MFMA: C[128n][8m], split-K 1024, in-kernel fp32->bf16 ----------------
__global__ __launch_bounds__(256) void head1_kernel(const float* __restrict__ hW1,
    const u16* __restrict__ ub, float* __restrict__ partial){
  __shared__ __align__(16) u16 As[128*64];
  __shared__ __align__(16) u16 Bs[16*64];
  int tid = threadIdx.x;
  int wave = __builtin_amdgcn_readfirstlane(tid>>6);
  int lane = tid & 63, quad = lane>>4, l16 = lane&15;
  int kc = blockIdx.x;              // 0..1023, KLEN=128
  int arow = tid & 127, apair = tid >> 7;
  floatx4 acc[2] = {};
  for (int sc = 0; sc < 2; sc++){
    int k0 = kc*128 + sc*64;
    const float* ap = hW1 + (size_t)arow*KTOT_ + k0 + apair*32;
    #pragma unroll
    for (int s = 0; s < 4; s++){
      float4 f0 = *(const float4*)(ap + s*8);
      float4 f1 = *(const float4*)(ap + s*8 + 4);
      union { u16 h[8]; int4 v; } pk;
      pk.h[0]=f2bf(f0.x); pk.h[1]=f2bf(f0.y); pk.h[2]=f2bf(f0.z); pk.h[3]=f2bf(f0.w);
      pk.h[4]=f2bf(f1.x); pk.h[5]=f2bf(f1.y); pk.h[6]=f2bf(f1.z); pk.h[7]=f2bf(f1.w);
      int seg = apair*4 + s;
      *(int4*)&As[arow*64 + ((seg^(arow&7))*8)] = pk.v;
    }
    if (tid < 128){
      int brow = tid >> 3, bseg = tid & 7;
      int4 bv = {0,0,0,0};
      if (brow < 8) bv = *(const int4*)&ub[(size_t)brow*KTOT_ + k0 + bseg*8];
      *(int4*)&Bs[brow*64 + ((bseg^(brow&7))*8)] = bv;
    }
    __syncthreads();
    #pragma unroll
    for (int kh = 0; kh < 2; kh++){
      short8 bf = *(short8*)&Bs[l16*64 + (((kh*4+quad)^(l16&7))*8)];
      #pragma unroll
      for (int i = 0; i < 2; i++){
        int row = wave*32 + i*16 + l16;
        short8 af = *(short8*)&As[row*64 + (((kh*4+quad)^(row&7))*8)];
        acc[i] = __builtin_amdgcn_mfma_f32_16x16x32_bf16(af, bf, acc[i], 0, 0, 0);
      }
    }
    __syncthreads();
  }
  if (l16 < 8){
    #pragma unroll
    for (int i = 0; i < 2; i++)
      #pragma unroll
      for (int r = 0; r < 4; r++){
        int n = wave*32 + i*16 + quad*4 + r;
        partial[(size_t)kc*1024 + n*8 + l16] = acc[i][r];
      }
  }
}

// stage 1: pp2[8][1024] = sum of 128 kc-partials each
__global__ void head_comb1_kernel(const float* __restrict__ partial, float* __restrict__ pp2){
  int out = blockIdx.x*256 + threadIdx.x;   // 0..1023
  int g = blockIdx.y;                        // 0..7
  const float* p = partial + (size_t)g*128*1024 + out;
  float s = 0.f;
  #pragma unroll 8
  for (int j = 0; j < 128; j++) s += p[(size_t)j*1024];
  pp2[g*1024 + out] = s;
}

// stage 2: t1[m*128+n] = gelu(hb1[n] + sum_g pp2)
__global__ void head_comb2_kernel(const float* __restrict__ pp2,
    const float* __restrict__ hb1, float* __restrict__ t1){
  int out = blockIdx.x*256 + threadIdx.x;   // 0..1023
  int n = out >> 3, m = out & 7;
  float s = hb1[n];
  #pragma unroll
  for (int g = 0; g < 8; g++) s += pp2[g*1024 + out];
  float ge = 0.5f*s*(1.f + erff(s*0.70710678118f));
  t1[m*128 + n] = ge;
}

__global__ void head2_kernel(const float* __restrict__ t1, const float* __restrict__ hW2,
                             const float* __restrict__ hb2, float* __restrict__ out){
  int idx = blockIdx.x*128 + threadIdx.x;  // 8*96
  if (idx >= B_*PRED_) return;
  int m = idx / PRED_, q = idx % PRED_;
  float s = hb2[q];
  #pragma unroll 16
  for (int k = 0; k < 2*CD_; k++) s += t1[m*128 + k]*hW2[q*128 + k];
  out[idx] = s;
}

// ---------------- prep: vectorized bf16 conversions + transposes ----------------
__global__ __launch_bounds__(256) void prep_kernel(const float* __restrict__ W_dt,
    const float* __restrict__ W_x, const float* __restrict__ W_in,
    const float* __restrict__ W_out, const float* __restrict__ peW,
    float* __restrict__ wdtT, u16* __restrict__ wxB,
    u16* __restrict__ WinB, u16* __restrict__ WoutB, u16* __restrict__ peWb){
  int idx = blockIdx.x*256 + threadIdx.x;   // 1,048,576 threads
  {
    float4 v = ((const float4*)W_in)[idx];
    ushort4 o = { f2bf(v.x), f2bf(v.y), f2bf(v.z), f2bf(v.w) };
    ((ushort4*)WinB)[idx] = o;
  }
  if (idx < 524288){
    float4 v = ((const float4*)W_out)[idx];
    ushort4 o = { f2bf(v.x), f2bf(v.y), f2bf(v.z), f2bf(v.w) };
    ((ushort4*)WoutB)[idx] = o;
  }
  if (idx < NL_*64*DI_/4){   // wxB: straight bf16 copy of W_x (NT layout already)
    float4 v = ((const float4*)W_x)[idx];
    ushort4 o = { f2bf(v.x), f2bf(v.y), f2bf(v.z), f2bf(v.w) };
    ((ushort4*)wxB)[idx] = o;
  }
  if (idx < NL_*DTR_*DI_){
    int l = idx / (DTR_*DI_); int rem = idx % (DTR_*DI_);
    int r = rem / DI_; int d = rem % DI_;
    wdtT[idx] = W_dt[((size_t)l*DI_ + d)*DTR_ + r];
  }
  if (idx < 512*128){
    int d = idx >> 7, kk = idx & 127;
    peWb[idx] = (kk < 112) ? f2bf(peW[d*112 + kk]) : (u16)0;
  }
}

extern "C" void kernel_launch(void* const* d_in, const int* in_sizes, int n_in,
                              void* d_out, int out_size, void* d_ws, size_t ws_size,
                              hipStream_t stream) {
  const float* x      = (const float*)d_in[0];
  const float* in_g   = (const float*)d_in[1];
  const float* in_b   = (const float*)d_in[2];
  const float* pe_W   = (const float*)d_in[3];
  const float* pe_b   = (const float*)d_in[4];
  const float* ln_g   = (const float*)d_in[5];
  const float* ln_b   = (const float*)d_in[6];
  const float* W_in   = (const float*)d_in[7];
  const float* conv_W = (const float*)d_in[8];
  const float* conv_b = (const float*)d_in[9];
  const float* W_x    = (const float*)d_in[10];
  const float* W_dt   = (const float*)d_in[11];
  const float* b_dt   = (const float*)d_in[12];
  const float* A_log  = (const float*)d_in[13];
  const float* Dskip  = (const float*)d_in[14];
  const float* W_out  = (const float*)d_in[15];
  const float* fn_g   = (const float*)d_in[16];
  const float* fn_b   = (const float*)d_in[17];
  const float* hW1    = (const float*)d_in[18];
  const float* hb1    = (const float*)d_in[19];
  const float* hW2    = (const float*)d_in[20];
  const float* hb2    = (const float*)d_in[21];

  float* ws    = (float*)d_ws;
  float* h     = ws;                    // 1,048,576 f
  float* un    = h     + 1048576;       // 1,048,576 f  (= dblpart scratch [8][2048][64])
  float* xz    = un    + 1048576;       // 4,194,304 f region (xzb u16 [2048][2048] = first half)
  float* xc    = xz    + 4194304;       // 2,097,152 f  (first half = xcb bf16)
  float* dblb  = xc    + 2097152;       //   131,072 f
  float* delta = dblb  + 131072;        // 2,097,152 f region (deltab u16 = first half)
  float* y     = delta + 2097152;       // 2,097,152 f  (overlays: xpb prologue, hend scan)
  float* wdtT  = y     + 2097152;       //   131,072 f
  u16*   wxB   = (u16*)(wdtT + 131072);         //   262,144 u16 (=131,072 f)
  float* bf_rgn= wdtT + 131072 + 131072;
  u16*   unb   = (u16*)bf_rgn;                  // 1,048,576 u16
  u16*   yb    = (u16*)(bf_rgn + 524288);       // 2,097,152 u16
  u16*   WinB  = (u16*)(bf_rgn + 524288 + 1048576);            // 4,194,304 u16
  u16*   WoutB = (u16*)(bf_rgn + 524288 + 1048576 + 2097152);  // 2,097,152 u16
  u16*   peWb  = (u16*)(bf_rgn + 524288 + 1048576 + 2097152 + 1048576); // 65,536 u16
  float* aprod = bf_rgn + 524288 + 1048576 + 2097152 + 1048576 + 32768; // 2,097,152 f
  // end ≈ 79.3 MB
  float* hend  = y;                     // [B*NCH][DI][NS]; becomes hin after pass B
  u16*   xcb   = (u16*)xc;              // bf16 xc [2048][1024] (alive through scan_final)
  u16*   xzb   = (u16*)xz;              // bf16 xz [2048][2048]
  u16*   deltab= (u16*)delta;           // bf16 delta [2048][1024]
  u16*   xpb   = (u16*)y;               // prologue-only: bf16 patches [2048][128]
  float* dblpart = un;                  // [8][2048][64] = 1,048,576 f (exact fit)
  float* partial = xz + 2097152;        // epilogue-only (1024*1024 = 1,048,576 f)
  float* pp2     = xz + 2097152 + 1048576; // 8,192 f
  float* t1      = xz + 2097152 + 1056768; // 1,024 f

  prep_kernel<<<4096, 256, 0, stream>>>(W_dt, W_x, W_in, W_out, pe_W,
                                        wdtT, wxB, WinB, WoutB, peWb);
  ln7_kernel<<<(B_*SEQ_+255)/256, 256, 0, stream>>>(x, in_g, in_b, xpb);
  // patch-embed as bf16 GEMM: h[2048][512] = xpb[2048][128] @ peWb[512][128]^T + pe_b
  gemm_bf16<64,128,false,true,false><<<dim3(DM_/128, TOK_/64), 256, 0, stream>>>(
      xpb, peWb, h, pe_b, 128, 128, 128, DM_);

  for (int l = 0; l < NL_; l++){
    ln512_kernel<<<TOK_/4, 256, 0, stream>>>(h, ln_g + l*DM_, ln_b + l*DM_, unb);
    gemm_bf16<128,128,false,false,true><<<dim3(2*DI_/128, TOK_/128), 256, 0, stream>>>(
        unb, WinB + (size_t)l*2*DI_*DM_, xzb, nullptr, DM_, DM_, DM_, 2*DI_);
    convdbl_kernel<<<dim3(TOK_/64, 8), 256, 0, stream>>>(
        xzb, conv_W + (size_t)l*DI_*DC_, conv_b + (size_t)l*DI_,
        wxB + (size_t)l*64*DI_, xcb, dblpart);
    dscan_kernel<<<dim3(DI_/256, B_*NCH_), 256, 0, stream>>>(
        dblpart, wdtT + (size_t)l*DTR_*DI_, b_dt + (size_t)l*DI_,
        xcb, A_log + (size_t)l*DI_*NS_, dblb, deltab, hend, aprod);
    scan_fix_kernel<<<(B_*DI_*NS_)/256, 256, 0, stream>>>(aprod, hend);
    scan_final_kernel<<<dim3(DI_/256, B_*NCH_), 256, 0, stream>>>(
        deltab, xcb, dblb, xzb, Dskip + (size_t)l*DI_, A_log + (size_t)l*DI_*NS_, hend, yb);
    gemm_bf16<64,64,true,false,false><<<dim3(DM_/64, TOK_/64), 256, 0, stream>>>(
        yb, WoutB + (size_t)l*DM_*DI_, h, nullptr, DI_, DI_, DI_, DM_);
  }

  ln512_kernel<<<TOK_/4, 256, 0, stream>>>(h, fn_g, fn_b, unb);
  head1_kernel<<<1024, 256, 0, stream>>>(hW1, unb, partial);
  head_comb1_kernel<<<dim3(4, 8), 256, 0, stream>>>(partial, pp2);
  head_comb2_kernel<<<4, 256, 0, stream>>>(pp2, hb1, t1);
  head2_kernel<<<6, 128, 0, stream>>>(t1, hW2, hb2, (float*)d_out);
}